// Round 20
// baseline (134.879 us; speedup 1.0000x reference)
//
#include <hip/hip_runtime.h>
#include <hip/hip_bf16.h>
#include <math.h>

// GateFusion via bf16 MFMA (16x16x32). r18's NT-wide-store win, rebuilt
// without the LDS transpose: phase-2 uses SWAPPED MFMA OPERANDS
// (mfma(W_frag, x_frag)) -> D^T fragments, so lane (cidx,kb) holds output
// row r0+cidx, channels s*16+kb*4..+3 -- one aligned dwordx4 NT store
// straight from the accumulator (no scratch, no bank conflicts; A/B 16x16
// fragments are lane-layout-identical so the same frag data serves both
// orientations). Scratch freed -> ALL 60 weight frags in LDS (61440B) ->
// compute has zero compiler-tracked VMEM -> clean counted-vmcnt 2-tile
// pipeline per wave (32 rows): burstA(+3 const loads inside the asm so no
// compiler vmcnt(0) ever drains us), burstB, WAIT(10)->compute0(8 NT
// stores), WAIT(8) (drains exactly burstB, keeps stores)->compute1.
// (r19 was this kernel with a macro-hygiene compile bug: asm symbolic
// operand names collided with macro parameter names.)
// out = g * (x_d@W_d) + (1-g) * (x_c@W_c),
// g = sigmoid( relu(LN(concat@Wg1)) @ Wg2 ),  per row.
//
// d_ws: fragment-linear bf16 weights; lane l of frag holds B[k(l,j)][n],
//   n = nt*16 + (l&15),  k(l,j) = ks*32 + (j>>2)*16 + (l>>4)*4 + (j&3)
// (coalesced-load k-map; identical permutation in A and B operands cancels).

namespace {

typedef __attribute__((ext_vector_type(8))) short short8;
typedef __attribute__((ext_vector_type(4))) float f32x4;

constexpr int CD = 64, CC = 96, CH = 64, CF = 128;
constexpr int NFG1 = 20;   // gate-weight frags
constexpr int NFCB = 40;   // output-weight frags
constexpr int NFRAG = NFG1 + NFCB;            // 60 frags = 61440 B
constexpr int WCH_ALL = NFRAG * 512 * 2 / 16; // 3840 x 16B

__device__ inline short bf16_of(float f) {
  __hip_bfloat16 h = __float2bfloat16(f);
  return *reinterpret_cast<short*>(&h);
}

__global__ void convert_weights(const float* __restrict__ Wd,
                                const float* __restrict__ Wc,
                                const float* __restrict__ Wg1,
                                short* __restrict__ ws) {
  const int t = blockIdx.x * 256 + threadIdx.x;
  if (t >= 64 * NFRAG) return;
  const int frag = t >> 6, l = t & 63;
  const int cidx = l & 15, kb = l >> 4;
  float v[8];
  if (frag < NFG1) {
    const int ks = frag >> 2, nt = frag & 3;
    const int n = nt * 16 + cidx;
    #pragma unroll
    for (int j = 0; j < 8; ++j) {
      const int k = ks * 32 + (j >> 2) * 16 + kb * 4 + (j & 3);
      v[j] = Wg1[k * CH + n];
    }
  } else {
    const int f2 = frag - NFG1;
    const int ks = f2 >> 3, nt = f2 & 7;
    const int n = nt * 16 + cidx;
    #pragma unroll
    for (int j = 0; j < 8; ++j) {
      const int k = ks * 32 + (j >> 2) * 16 + kb * 4 + (j & 3);
      v[j] = (k < CD) ? Wd[k * CF + n] : Wc[(k - CD) * CF + n];
    }
  }
  short8 o;
  #pragma unroll
  for (int j = 0; j < 8; ++j) o[j] = bf16_of(v[j]);
  *reinterpret_cast<short8*>(ws + frag * 512 + l * 8) = o;
}

// burst A: 10 x-loads + 3 per-lane const dwords, one immovable block.
// NOTE: asm symbolic names ([ad],[ac],[sg],[sb],[sw],[og],[ob],[ow]) must
// not collide with macro parameter names (r19 compile bug).
#define BURSTA(p0,p1,p2,p3,p4,p5,p6,p7,p8,p9, g0,g1,g2, rdp, rcp, pg, pb, pw) \
  asm volatile(                                                        \
      "global_load_dwordx4 %0, %[ad], off\n\t"                         \
      "global_load_dwordx4 %1, %[ad], off offset:64\n\t"               \
      "global_load_dwordx4 %2, %[ad], off offset:128\n\t"              \
      "global_load_dwordx4 %3, %[ad], off offset:192\n\t"              \
      "global_load_dwordx4 %4, %[ac], off\n\t"                         \
      "global_load_dwordx4 %5, %[ac], off offset:64\n\t"               \
      "global_load_dwordx4 %6, %[ac], off offset:128\n\t"              \
      "global_load_dwordx4 %7, %[ac], off offset:192\n\t"              \
      "global_load_dwordx4 %8, %[ac], off offset:256\n\t"              \
      "global_load_dwordx4 %9, %[ac], off offset:320\n\t"              \
      "global_load_dword %[og], %[sg], off\n\t"                        \
      "global_load_dword %[ob], %[sb], off\n\t"                        \
      "global_load_dword %[ow], %[sw], off"                            \
      : "=&v"(p0), "=&v"(p1), "=&v"(p2), "=&v"(p3), "=&v"(p4),         \
        "=&v"(p5), "=&v"(p6), "=&v"(p7), "=&v"(p8), "=&v"(p9),         \
        [og] "=&v"(g0), [ob] "=&v"(g1), [ow] "=&v"(g2)                 \
      : [ad] "v"(rdp), [ac] "v"(rcp), [sg] "v"(pg), [sb] "v"(pb),      \
        [sw] "v"(pw)                                                   \
      : "memory")

#define BURSTB(p0,p1,p2,p3,p4,p5,p6,p7,p8,p9, rdp, rcp)                \
  asm volatile(                                                        \
      "global_load_dwordx4 %0, %[ad], off\n\t"                         \
      "global_load_dwordx4 %1, %[ad], off offset:64\n\t"               \
      "global_load_dwordx4 %2, %[ad], off offset:128\n\t"              \
      "global_load_dwordx4 %3, %[ad], off offset:192\n\t"              \
      "global_load_dwordx4 %4, %[ac], off\n\t"                         \
      "global_load_dwordx4 %5, %[ac], off offset:64\n\t"               \
      "global_load_dwordx4 %6, %[ac], off offset:128\n\t"              \
      "global_load_dwordx4 %7, %[ac], off offset:192\n\t"              \
      "global_load_dwordx4 %8, %[ac], off offset:256\n\t"              \
      "global_load_dwordx4 %9, %[ac], off offset:320"                  \
      : "=&v"(p0), "=&v"(p1), "=&v"(p2), "=&v"(p3), "=&v"(p4),         \
        "=&v"(p5), "=&v"(p6), "=&v"(p7), "=&v"(p8), "=&v"(p9)          \
      : [ad] "v"(rdp), [ac] "v"(rcp)                                   \
      : "memory")

#define WAITA(N, p0,p1,p2,p3,p4,p5,p6,p7,p8,p9, g0,g1,g2)              \
  asm volatile("s_waitcnt vmcnt(" #N ")"                               \
      : "+v"(p0), "+v"(p1), "+v"(p2), "+v"(p3), "+v"(p4),              \
        "+v"(p5), "+v"(p6), "+v"(p7), "+v"(p8), "+v"(p9),              \
        "+v"(g0), "+v"(g1), "+v"(g2)                                   \
      :: "memory")

#define WAITN(N, p0,p1,p2,p3,p4,p5,p6,p7,p8,p9)                        \
  asm volatile("s_waitcnt vmcnt(" #N ")"                               \
      : "+v"(p0), "+v"(p1), "+v"(p2), "+v"(p3), "+v"(p4),              \
        "+v"(p5), "+v"(p6), "+v"(p7), "+v"(p8), "+v"(p9)               \
      :: "memory")

__global__ __launch_bounds__(512)
void gate_fusion_mfma(const float* __restrict__ xd,
                      const float* __restrict__ xc,
                      const float* __restrict__ gma,
                      const float* __restrict__ bta,
                      const float* __restrict__ Wg2,
                      const short* __restrict__ wf,
                      float* __restrict__ out, int N) {
  __shared__ short wlds[NFRAG * 512];   // 61440 B

  const int tid  = threadIdx.x;
  const int lane = tid & 63;
  const int wv   = tid >> 6;                 // 0..7
  const int cidx = lane & 15;
  const int kb   = lane >> 4;
  const int r0   = blockIdx.x * 256 + wv * 32;   // 32 rows per wave
  const bool active = (r0 < N);              // N % 32 == 0

  // ---- stage all 60 weight frags (compiler VMEM; drained before barrier)
  for (int c = tid; c < WCH_ALL; c += 512) {
    short8 v = *reinterpret_cast<const short8*>(wf + (size_t)c * 8);
    *reinterpret_cast<short8*>(&wlds[c * 8]) = v;
  }
  __syncthreads();   // the only barrier
  if (!active) return;

  const f32x4 vzero = {0.f, 0.f, 0.f, 0.f};

  // ---- compute one 16-row tile; phase-2 operand-swapped -> direct NT store
  auto compute = [&](int rr0, const f32x4* lo, const f32x4* hi,
                     const float* gmv, const float* btv, const float* w2v) {
    short8 xf[5];
    #pragma unroll
    for (int ks = 0; ks < 5; ++ks) {
      short8 f;
      #pragma unroll
      for (int j = 0; j < 4; ++j) {
        f[j]     = bf16_of(lo[ks][j]);
        f[4 + j] = bf16_of(hi[ks][j]);
      }
      xf[ks] = f;
    }

    // phase 1 (normal orientation): h = x @ Wg1, C-layout rows kb*4+r
    f32x4 acc1[4];
    #pragma unroll
    for (int nt = 0; nt < 4; ++nt) acc1[nt] = vzero;
    #pragma unroll
    for (int ks = 0; ks < 5; ++ks) {
      short8 bg[4];
      #pragma unroll
      for (int nt = 0; nt < 4; ++nt)
        bg[nt] = *reinterpret_cast<const short8*>(
            &wlds[(ks * 4 + nt) * 512 + lane * 8]);
      #pragma unroll
      for (int nt = 0; nt < 4; ++nt)
        acc1[nt] = __builtin_amdgcn_mfma_f32_16x16x32_bf16(
            xf[ks], bg[nt], acc1[nt], 0, 0, 0);
    }

    // LayerNorm + relu + dot(Wg2) + sigmoid
    float gate[4];
    {
      float s[4], q[4];
      #pragma unroll
      for (int r = 0; r < 4; ++r) {
        s[r] = 0.f; q[r] = 0.f;
        #pragma unroll
        for (int nt = 0; nt < 4; ++nt) {
          const float c = acc1[nt][r];
          s[r] += c; q[r] += c * c;
        }
      }
      #pragma unroll
      for (int m = 1; m < 16; m <<= 1)
        #pragma unroll
        for (int r = 0; r < 4; ++r) {
          s[r] += __shfl_xor(s[r], m, 64);
          q[r] += __shfl_xor(q[r], m, 64);
        }
      float p[4];
      #pragma unroll
      for (int r = 0; r < 4; ++r) {
        const float mu  = s[r] * (1.f / CH);
        const float var = q[r] * (1.f / CH) - mu * mu;
        const float rsd = rsqrtf(var + 1e-5f);
        float pp = 0.f;
        #pragma unroll
        for (int nt = 0; nt < 4; ++nt) {
          const float h = fmaxf((acc1[nt][r] - mu) * rsd * gmv[nt] + btv[nt], 0.f);
          pp += h * w2v[nt];
        }
        p[r] = pp;
      }
      #pragma unroll
      for (int m = 1; m < 16; m <<= 1)
        #pragma unroll
        for (int r = 0; r < 4; ++r) p[r] += __shfl_xor(p[r], m, 64);
      #pragma unroll
      for (int r = 0; r < 4; ++r) gate[r] = 1.f / (1.f + expf(-p[r]));
    }

    // redistribute gate to row-per-lane (row = cidx): gate[r] is uniform
    // across cidx within a kb group, so pull from lane (cidx>>2)*16.
    float g4[4];
    #pragma unroll
    for (int r = 0; r < 4; ++r) g4[r] = __shfl(gate[r], (cidx >> 2) << 4);
    const int rs = cidx & 3;
    const float g_row = rs == 3 ? g4[3] : rs == 2 ? g4[2] : rs == 1 ? g4[1] : g4[0];

    // phase 2 swapped: D^T -> lane holds row rr0+cidx, chans s*16+kb*4..+3
    #pragma unroll
    for (int s = 0; s < 8; ++s) {
      f32x4 aD = vzero, aC = vzero;
      #pragma unroll
      for (int ks = 0; ks < 5; ++ks) {
        short8 bg = *reinterpret_cast<const short8*>(
            &wlds[(NFG1 + ks * 8 + s) * 512 + lane * 8]);
        if (ks < 2)
          aD = __builtin_amdgcn_mfma_f32_16x16x32_bf16(bg, xf[ks], aD, 0, 0, 0);
        else
          aC = __builtin_amdgcn_mfma_f32_16x16x32_bf16(bg, xf[ks], aC, 0, 0, 0);
      }
      f32x4 o;
      #pragma unroll
      for (int r = 0; r < 4; ++r) o[r] = fmaf(g_row, aD[r] - aC[r], aC[r]);
      float* dst = &out[((size_t)rr0 + cidx) * CF + s * 16 + kb * 4];
      asm volatile("global_store_dwordx4 %0, %1, off nt"
                   :: "v"(dst), "v"(o) : "memory");
    }
  };

  // ---- 2-tile pipeline, straight-line
  f32x4 a0,a1,a2,a3,a4,a5,a6,a7,a8,a9, b0,b1,b2,b3,b4,b5,b6,b7,b8,b9;
  float gaL, baL, waL;
  {
    const float* rdp0 = xd + ((size_t)r0 + cidx) * CD + kb * 4;
    const float* rcp0 = xc + ((size_t)r0 + cidx) * CC + kb * 4;
    BURSTA(a0,a1,a2,a3,a4,a5,a6,a7,a8,a9, gaL,baL,waL,
           rdp0, rcp0, gma + lane, bta + lane, Wg2 + lane);
    const float* rdp1 = xd + ((size_t)r0 + 16 + cidx) * CD + kb * 4;
    const float* rcp1 = xc + ((size_t)r0 + 16 + cidx) * CC + kb * 4;
    BURSTB(b0,b1,b2,b3,b4,b5,b6,b7,b8,b9, rdp1, rcp1);
  }

  WAITA(10, a0,a1,a2,a3,a4,a5,a6,a7,a8,a9, gaL,baL,waL);  // A done, B flying
  __builtin_amdgcn_sched_barrier(0);

  float gmv[4], btv[4], w2v[4];
  #pragma unroll
  for (int nt = 0; nt < 4; ++nt) {
    gmv[nt] = __shfl(gaL, nt * 16 + cidx);
    btv[nt] = __shfl(baL, nt * 16 + cidx);
    w2v[nt] = __shfl(waL, nt * 16 + cidx);
  }

  {
    const f32x4 lo0[5] = {a0, a2, a4, a6, a8};
    const f32x4 hi0[5] = {a1, a3, a5, a7, a9};
    compute(r0, lo0, hi0, gmv, btv, w2v);       // issues 8 NT stores
  }

  WAITN(8, b0,b1,b2,b3,b4,b5,b6,b7,b8,b9);      // drains B; keeps the 8 stores
  __builtin_amdgcn_sched_barrier(0);

  {
    const f32x4 lo1[5] = {b0, b2, b4, b6, b8};
    const f32x4 hi1[5] = {b1, b3, b5, b7, b9};
    compute(r0 + 16, lo1, hi1, gmv, btv, w2v);
  }
}

}  // namespace

extern "C" void kernel_launch(void* const* d_in, const int* in_sizes, int n_in,
                              void* d_out, int out_size, void* d_ws, size_t ws_size,
                              hipStream_t stream) {
  const float* xd  = (const float*)d_in[0];
  const float* xc  = (const float*)d_in[1];
  const float* Wd  = (const float*)d_in[2];
  const float* Wc  = (const float*)d_in[3];
  const float* Wg1 = (const float*)d_in[4];
  const float* gma = (const float*)d_in[5];
  const float* bta = (const float*)d_in[6];
  const float* Wg2 = (const float*)d_in[7];
  float* out = (float*)d_out;
  short* ws  = (short*)d_ws;   // needs 60 KB

  const int N = in_sizes[0] / CD;

  convert_weights<<<dim3(15), dim3(256), 0, stream>>>(Wd, Wc, Wg1, ws);

  const int nblk = (N + 255) / 256;   // 256 rows per 8-wave block
  gate_fusion_mfma<<<dim3(nblk), dim3(512), 0, stream>>>(
      xd, xc, gma, bta, Wg2, ws, out, N);
}

// Round 22
// 126.450 us; speedup vs baseline: 1.0667x; 1.0667x over previous
//
#include <hip/hip_runtime.h>
#include <hip/hip_bf16.h>
#include <math.h>

// GateFusion via bf16 MFMA (16x16x32). r18 proven kernel (126.8us, exact
// traffic) with ONE change: transpose-scratch row padded 132 -> 136 floats.
// Bank math: write banks are cidx + (pad%32/4)*kb; pad=132 gives 4*kb ->
// 4-way collisions (r18's 2M SQ_LDS_BANK_CONFLICT); pad=136 gives 8*kb ->
// exactly 2 lanes/bank everywhere, and 2-way is free on CDNA4.
// r21 lesson (correctness failure): inline-asm async loads whose live range
// spans heavy compute are unsound -- regalloc may spill/copy in-flight
// registers. Cross-tile register pipelining is closed; one-shot structure.
// out = g * (x_d@W_d) + (1-g) * (x_c@W_c),
// g = sigmoid( relu(LN(concat@Wg1)) @ Wg2 ),  per row.
//
// d_ws: fragment-linear bf16 weights; lane l of frag holds B[k(l,j)][n],
//   n = nt*16 + (l&15),  k(l,j) = ks*32 + (j>>2)*16 + (l>>4)*4 + (j&3)
// (coalesced-load k-map; identical permutation in A and B operands cancels).

namespace {

typedef __attribute__((ext_vector_type(8))) short short8;
typedef __attribute__((ext_vector_type(4))) float f32x4;

constexpr int CD = 64, CC = 96, CH = 64, CF = 128;
constexpr int NFG1 = 20;   // gate-weight frags (read from L1/L2)
constexpr int NFCB = 40;   // output-weight frags (staged in LDS)
constexpr int NFRAG = NFG1 + NFCB;
constexpr int WCHUNKS = NFCB * 512 * 2 / 16;  // 2560 x 16B = 40960 B

__device__ inline short bf16_of(float f) {
  __hip_bfloat16 h = __float2bfloat16(f);
  return *reinterpret_cast<short*>(&h);
}

__global__ void convert_weights(const float* __restrict__ Wd,
                                const float* __restrict__ Wc,
                                const float* __restrict__ Wg1,
                                short* __restrict__ ws) {
  const int t = blockIdx.x * 256 + threadIdx.x;
  if (t >= 64 * NFRAG) return;
  const int frag = t >> 6, l = t & 63;
  const int cidx = l & 15, kb = l >> 4;
  float v[8];
  if (frag < NFG1) {
    const int ks = frag >> 2, nt = frag & 3;
    const int n = nt * 16 + cidx;
    #pragma unroll
    for (int j = 0; j < 8; ++j) {
      const int k = ks * 32 + (j >> 2) * 16 + kb * 4 + (j & 3);
      v[j] = Wg1[k * CH + n];
    }
  } else {
    const int f2 = frag - NFG1;
    const int ks = f2 >> 3, nt = f2 & 7;
    const int n = nt * 16 + cidx;
    #pragma unroll
    for (int j = 0; j < 8; ++j) {
      const int k = ks * 32 + (j >> 2) * 16 + kb * 4 + (j & 3);
      v[j] = (k < CD) ? Wd[k * CF + n] : Wc[(k - CD) * CF + n];
    }
  }
  short8 o;
  #pragma unroll
  for (int j = 0; j < 8; ++j) o[j] = bf16_of(v[j]);
  *reinterpret_cast<short8*>(ws + frag * 512 + l * 8) = o;
}

__global__ __launch_bounds__(512, 4)
void gate_fusion_mfma(const float* __restrict__ xd,
                      const float* __restrict__ xc,
                      const float* __restrict__ gma,
                      const float* __restrict__ bta,
                      const float* __restrict__ Wg2,
                      const short* __restrict__ wf,
                      float* __restrict__ out, int N) {
  __shared__ short wlds[NFCB * 512];     // 40960 B
  __shared__ float tr[8][4][136];        // 17408 B: padded transpose scratch

  const int tid  = threadIdx.x;
  const int lane = tid & 63;
  const int wv   = tid >> 6;                 // 0..7
  const int r0   = blockIdx.x * 128 + wv * 16;   // 16 rows per wave
  const int cidx = lane & 15;
  const int kb   = lane >> 4;
  const bool active = (r0 < N);              // wave-uniform (N % 16 == 0)

  // ---- x loads (coalesced 64B/4-lane segments, r14 k-map)
  f32x4 buf[5][2];
  if (active) {
    const size_t row = (size_t)(r0 + cidx);
    const float* rd = xd + row * CD + kb * 4;
    const float* rc = xc + row * CC + kb * 4;
    #pragma unroll
    for (int ks = 0; ks < 5; ++ks) {
      const float* p = (ks < 2) ? (rd + ks * 32) : (rc + (ks - 2) * 32);
      buf[ks][0] = *reinterpret_cast<const f32x4*>(p);
      buf[ks][1] = *reinterpret_cast<const f32x4*>(p + 16);
    }
  }

  // ---- stage the 40 output-weight frags (40960 B) into LDS
  {
    const short* wsrc = wf + NFG1 * 512;
    #pragma unroll
    for (int it = 0; it < WCHUNKS / 512; ++it) {
      const int c = tid + it * 512;
      short8 v = *reinterpret_cast<const short8*>(wsrc + (size_t)c * 8);
      *reinterpret_cast<short8*>(&wlds[c * 8]) = v;
    }
  }

  __syncthreads();
  if (!active) return;   // after the only barrier

  // per-wave constants (cache-hit loads)
  float gmv[4], btv[4], w2v[4];
  #pragma unroll
  for (int nt = 0; nt < 4; ++nt) {
    const int c = nt * 16 + cidx;
    gmv[nt] = gma[c]; btv[nt] = bta[c]; w2v[nt] = Wg2[c];
  }

  // ---- convert x to bf16 A-fragments
  short8 xf[5];
  #pragma unroll
  for (int ks = 0; ks < 5; ++ks) {
    short8 f;
    #pragma unroll
    for (int j = 0; j < 4; ++j) {
      f[j]     = bf16_of(buf[ks][0][j]);
      f[4 + j] = bf16_of(buf[ks][1][j]);
    }
    xf[ks] = f;
  }

  // ---- phase 1: h = x @ Wg1  [16 x 64]  (B-frags from L1/L2)
  const f32x4 vzero = {0.f, 0.f, 0.f, 0.f};
  f32x4 acc1[4];
  #pragma unroll
  for (int nt = 0; nt < 4; ++nt) acc1[nt] = vzero;

  #pragma unroll
  for (int ks = 0; ks < 5; ++ks) {
    short8 bg[4];
    #pragma unroll
    for (int nt = 0; nt < 4; ++nt)
      bg[nt] = *reinterpret_cast<const short8*>(wf + (ks * 4 + nt) * 512 + lane * 8);
    #pragma unroll
    for (int nt = 0; nt < 4; ++nt)
      acc1[nt] = __builtin_amdgcn_mfma_f32_16x16x32_bf16(
          xf[ks], bg[nt], acc1[nt], 0, 0, 0);
  }

  // ---- LayerNorm + relu + dot(Wg2) + sigmoid (C-fragment layout)
  float gate[4];
  {
    float s[4], q[4];
    #pragma unroll
    for (int r = 0; r < 4; ++r) {
      s[r] = 0.f; q[r] = 0.f;
      #pragma unroll
      for (int nt = 0; nt < 4; ++nt) {
        const float c = acc1[nt][r];
        s[r] += c; q[r] += c * c;
      }
    }
    #pragma unroll
    for (int m = 1; m < 16; m <<= 1)
      #pragma unroll
      for (int r = 0; r < 4; ++r) {
        s[r] += __shfl_xor(s[r], m, 64);
        q[r] += __shfl_xor(q[r], m, 64);
      }
    float p[4];
    #pragma unroll
    for (int r = 0; r < 4; ++r) {
      const float mu  = s[r] * (1.f / CH);
      const float var = q[r] * (1.f / CH) - mu * mu;
      const float rsd = rsqrtf(var + 1e-5f);
      float pp = 0.f;
      #pragma unroll
      for (int nt = 0; nt < 4; ++nt) {
        const float h = fmaxf((acc1[nt][r] - mu) * rsd * gmv[nt] + btv[nt], 0.f);
        pp += h * w2v[nt];
      }
      p[r] = pp;
    }
    #pragma unroll
    for (int m = 1; m < 16; m <<= 1)
      #pragma unroll
      for (int r = 0; r < 4; ++r) p[r] += __shfl_xor(p[r], m, 64);
    #pragma unroll
    for (int r = 0; r < 4; ++r) gate[r] = 1.f / (1.f + expf(-p[r]));
  }

  // ---- phase 2: all 4 nt-quarter slices, blended results kept in registers
  f32x4 o[4][2];
  #pragma unroll
  for (int q = 0; q < 4; ++q) {
    f32x4 aD[2], aC[2];
    #pragma unroll
    for (int nt = 0; nt < 2; ++nt) { aD[nt] = vzero; aC[nt] = vzero; }

    #pragma unroll
    for (int ks = 0; ks < 5; ++ks) {
      short8 bg[2];
      #pragma unroll
      for (int nt = 0; nt < 2; ++nt)
        bg[nt] = *reinterpret_cast<const short8*>(
            &wlds[(ks * 8 + q * 2 + nt) * 512 + lane * 8]);
      if (ks < 2) {
        #pragma unroll
        for (int nt = 0; nt < 2; ++nt)
          aD[nt] = __builtin_amdgcn_mfma_f32_16x16x32_bf16(
              xf[ks], bg[nt], aD[nt], 0, 0, 0);
      } else {
        #pragma unroll
        for (int nt = 0; nt < 2; ++nt)
          aC[nt] = __builtin_amdgcn_mfma_f32_16x16x32_bf16(
              xf[ks], bg[nt], aC[nt], 0, 0, 0);
      }
    }
    #pragma unroll
    for (int nt = 0; nt < 2; ++nt)
      #pragma unroll
      for (int r = 0; r < 4; ++r)
        o[q][nt][r] = fmaf(gate[r], aD[nt][r] - aC[nt][r], aC[nt][r]);
  }

  // ---- transpose via per-wave LDS scratch + wide NT stores.
  // Fragment layout: o[q][nt][r] is row kb*4+r, col (q*2+nt)*16+cidx.
  // For each r: scratch[kb][col] <- o[..][..][r]; then 2 insts store
  // rows {r0+0*4+r .. r0+3*4+r} as 512B-contiguous dwordx4 nt.
  {
    float (*trw)[136] = tr[wv];
    #pragma unroll
    for (int r = 0; r < 4; ++r) {
      #pragma unroll
      for (int q = 0; q < 4; ++q)
        #pragma unroll
        for (int nt = 0; nt < 2; ++nt)
          trw[kb][(q * 2 + nt) * 16 + cidx] = o[q][nt][r];
      // same-wave LDS write->read: in-order DS pipe + compiler lgkmcnt
      #pragma unroll
      for (int i = 0; i < 2; ++i) {
        const int ri = i * 2 + (lane >> 5);          // scratch row 0..3
        const f32x4 v = *reinterpret_cast<const f32x4*>(
            &trw[ri][(lane & 31) * 4]);
        float* dst = &out[((size_t)r0 + ri * 4 + r) * CF + (lane & 31) * 4];
        asm volatile("global_store_dwordx4 %0, %1, off nt"
                     :: "v"(dst), "v"(v) : "memory");
      }
    }
  }
}

}  // namespace

extern "C" void kernel_launch(void* const* d_in, const int* in_sizes, int n_in,
                              void* d_out, int out_size, void* d_ws, size_t ws_size,
                              hipStream_t stream) {
  const float* xd  = (const float*)d_in[0];
  const float* xc  = (const float*)d_in[1];
  const float* Wd  = (const float*)d_in[2];
  const float* Wc  = (const float*)d_in[3];
  const float* Wg1 = (const float*)d_in[4];
  const float* gma = (const float*)d_in[5];
  const float* bta = (const float*)d_in[6];
  const float* Wg2 = (const float*)d_in[7];
  float* out = (float*)d_out;
  short* ws  = (short*)d_ws;   // needs 60 KB

  const int N = in_sizes[0] / CD;

  convert_weights<<<dim3(15), dim3(256), 0, stream>>>(Wd, Wc, Wg1, ws);

  const int nblk = (N + 127) / 128;   // 128 rows per 8-wave block
  gate_fusion_mfma<<<dim3(nblk), dim3(512), 0, stream>>>(
      xd, xc, gma, bta, Wg2, ws, out, N);
}

// Round 23
// 114.989 us; speedup vs baseline: 1.1730x; 1.0997x over previous
//
#include <hip/hip_runtime.h>
#include <hip/hip_bf16.h>
#include <math.h>

// GateFusion via bf16 MFMA (16x16x32). r22 proven kernel (126.5us, exact
// traffic, NT 512B-contiguous stores) with ONE change: ALL 60 weight frags
// staged in LDS (61440B + 17408B scratch = 78848B, still 2 blocks/CU), so
// phase-1's B-fragments come from LDS instead of global/L2. Rationale: at
// VGPR=52 the compiler can't hoist the 5 dependent batches of 4 L2 frag
// loads in phase 1 -> ~1200+ cycles of exposed L2 latency per tile on the
// MFMA critical path. This is the last untested serial-latency component.
// out = g * (x_d@W_d) + (1-g) * (x_c@W_c),
// g = sigmoid( relu(LN(concat@Wg1)) @ Wg2 ),  per row.
//
// d_ws: fragment-linear bf16 weights; lane l of frag holds B[k(l,j)][n],
//   n = nt*16 + (l&15),  k(l,j) = ks*32 + (j>>2)*16 + (l>>4)*4 + (j&3)
// (coalesced-load k-map; identical permutation in A and B operands cancels).

namespace {

typedef __attribute__((ext_vector_type(8))) short short8;
typedef __attribute__((ext_vector_type(4))) float f32x4;

constexpr int CD = 64, CC = 96, CH = 64, CF = 128;
constexpr int NFG1 = 20;   // gate-weight frags
constexpr int NFCB = 40;   // output-weight frags
constexpr int NFRAG = NFG1 + NFCB;            // 60 frags = 61440 B
constexpr int WCH_ALL = NFRAG * 512 * 2 / 16; // 3840 x 16B

__device__ inline short bf16_of(float f) {
  __hip_bfloat16 h = __float2bfloat16(f);
  return *reinterpret_cast<short*>(&h);
}

__global__ void convert_weights(const float* __restrict__ Wd,
                                const float* __restrict__ Wc,
                                const float* __restrict__ Wg1,
                                short* __restrict__ ws) {
  const int t = blockIdx.x * 256 + threadIdx.x;
  if (t >= 64 * NFRAG) return;
  const int frag = t >> 6, l = t & 63;
  const int cidx = l & 15, kb = l >> 4;
  float v[8];
  if (frag < NFG1) {
    const int ks = frag >> 2, nt = frag & 3;
    const int n = nt * 16 + cidx;
    #pragma unroll
    for (int j = 0; j < 8; ++j) {
      const int k = ks * 32 + (j >> 2) * 16 + kb * 4 + (j & 3);
      v[j] = Wg1[k * CH + n];
    }
  } else {
    const int f2 = frag - NFG1;
    const int ks = f2 >> 3, nt = f2 & 7;
    const int n = nt * 16 + cidx;
    #pragma unroll
    for (int j = 0; j < 8; ++j) {
      const int k = ks * 32 + (j >> 2) * 16 + kb * 4 + (j & 3);
      v[j] = (k < CD) ? Wd[k * CF + n] : Wc[(k - CD) * CF + n];
    }
  }
  short8 o;
  #pragma unroll
  for (int j = 0; j < 8; ++j) o[j] = bf16_of(v[j]);
  *reinterpret_cast<short8*>(ws + frag * 512 + l * 8) = o;
}

__global__ __launch_bounds__(512, 2)
void gate_fusion_mfma(const float* __restrict__ xd,
                      const float* __restrict__ xc,
                      const float* __restrict__ gma,
                      const float* __restrict__ bta,
                      const float* __restrict__ Wg2,
                      const short* __restrict__ wf,
                      float* __restrict__ out, int N) {
  __shared__ short wlds[NFRAG * 512];    // 61440 B: ALL 60 weight frags
  __shared__ float tr[8][4][136];        // 17408 B: padded transpose scratch

  const int tid  = threadIdx.x;
  const int lane = tid & 63;
  const int wv   = tid >> 6;                 // 0..7
  const int r0   = blockIdx.x * 128 + wv * 16;   // 16 rows per wave
  const int cidx = lane & 15;
  const int kb   = lane >> 4;
  const bool active = (r0 < N);              // wave-uniform (N % 16 == 0)

  // ---- x loads (coalesced 64B/4-lane segments, r14 k-map)
  f32x4 buf[5][2];
  if (active) {
    const size_t row = (size_t)(r0 + cidx);
    const float* rd = xd + row * CD + kb * 4;
    const float* rc = xc + row * CC + kb * 4;
    #pragma unroll
    for (int ks = 0; ks < 5; ++ks) {
      const float* p = (ks < 2) ? (rd + ks * 32) : (rc + (ks - 2) * 32);
      buf[ks][0] = *reinterpret_cast<const f32x4*>(p);
      buf[ks][1] = *reinterpret_cast<const f32x4*>(p + 16);
    }
  }

  // ---- stage all 60 weight frags (61440 B) into LDS
  {
    #pragma unroll
    for (int it = 0; it < 8; ++it) {
      const int c = tid + it * 512;
      if (it < 7 || c < WCH_ALL) {
        short8 v = *reinterpret_cast<const short8*>(wf + (size_t)c * 8);
        *reinterpret_cast<short8*>(&wlds[c * 8]) = v;
      }
    }
  }

  __syncthreads();
  if (!active) return;   // after the only barrier

  // per-wave constants (cache-hit loads)
  float gmv[4], btv[4], w2v[4];
  #pragma unroll
  for (int nt = 0; nt < 4; ++nt) {
    const int c = nt * 16 + cidx;
    gmv[nt] = gma[c]; btv[nt] = bta[c]; w2v[nt] = Wg2[c];
  }

  // ---- convert x to bf16 A-fragments
  short8 xf[5];
  #pragma unroll
  for (int ks = 0; ks < 5; ++ks) {
    short8 f;
    #pragma unroll
    for (int j = 0; j < 4; ++j) {
      f[j]     = bf16_of(buf[ks][0][j]);
      f[4 + j] = bf16_of(buf[ks][1][j]);
    }
    xf[ks] = f;
  }

  // ---- phase 1: h = x @ Wg1  [16 x 64]  (B-frags from LDS now)
  const f32x4 vzero = {0.f, 0.f, 0.f, 0.f};
  f32x4 acc1[4];
  #pragma unroll
  for (int nt = 0; nt < 4; ++nt) acc1[nt] = vzero;

  #pragma unroll
  for (int ks = 0; ks < 5; ++ks) {
    short8 bg[4];
    #pragma unroll
    for (int nt = 0; nt < 4; ++nt)
      bg[nt] = *reinterpret_cast<const short8*>(
          &wlds[(ks * 4 + nt) * 512 + lane * 8]);
    #pragma unroll
    for (int nt = 0; nt < 4; ++nt)
      acc1[nt] = __builtin_amdgcn_mfma_f32_16x16x32_bf16(
          xf[ks], bg[nt], acc1[nt], 0, 0, 0);
  }

  // ---- LayerNorm + relu + dot(Wg2) + sigmoid (C-fragment layout)
  float gate[4];
  {
    float s[4], q[4];
    #pragma unroll
    for (int r = 0; r < 4; ++r) {
      s[r] = 0.f; q[r] = 0.f;
      #pragma unroll
      for (int nt = 0; nt < 4; ++nt) {
        const float c = acc1[nt][r];
        s[r] += c; q[r] += c * c;
      }
    }
    #pragma unroll
    for (int m = 1; m < 16; m <<= 1)
      #pragma unroll
      for (int r = 0; r < 4; ++r) {
        s[r] += __shfl_xor(s[r], m, 64);
        q[r] += __shfl_xor(q[r], m, 64);
      }
    float p[4];
    #pragma unroll
    for (int r = 0; r < 4; ++r) {
      const float mu  = s[r] * (1.f / CH);
      const float var = q[r] * (1.f / CH) - mu * mu;
      const float rsd = rsqrtf(var + 1e-5f);
      float pp = 0.f;
      #pragma unroll
      for (int nt = 0; nt < 4; ++nt) {
        const float h = fmaxf((acc1[nt][r] - mu) * rsd * gmv[nt] + btv[nt], 0.f);
        pp += h * w2v[nt];
      }
      p[r] = pp;
    }
    #pragma unroll
    for (int m = 1; m < 16; m <<= 1)
      #pragma unroll
      for (int r = 0; r < 4; ++r) p[r] += __shfl_xor(p[r], m, 64);
    #pragma unroll
    for (int r = 0; r < 4; ++r) gate[r] = 1.f / (1.f + expf(-p[r]));
  }

  // ---- phase 2: all 4 nt-quarter slices, blended results kept in registers
  f32x4 o[4][2];
  #pragma unroll
  for (int q = 0; q < 4; ++q) {
    f32x4 aD[2], aC[2];
    #pragma unroll
    for (int nt = 0; nt < 2; ++nt) { aD[nt] = vzero; aC[nt] = vzero; }

    #pragma unroll
    for (int ks = 0; ks < 5; ++ks) {
      short8 bg[2];
      #pragma unroll
      for (int nt = 0; nt < 2; ++nt)
        bg[nt] = *reinterpret_cast<const short8*>(
            &wlds[(NFG1 + ks * 8 + q * 2 + nt) * 512 + lane * 8]);
      if (ks < 2) {
        #pragma unroll
        for (int nt = 0; nt < 2; ++nt)
          aD[nt] = __builtin_amdgcn_mfma_f32_16x16x32_bf16(
              xf[ks], bg[nt], aD[nt], 0, 0, 0);
      } else {
        #pragma unroll
        for (int nt = 0; nt < 2; ++nt)
          aC[nt] = __builtin_amdgcn_mfma_f32_16x16x32_bf16(
              xf[ks], bg[nt], aC[nt], 0, 0, 0);
      }
    }
    #pragma unroll
    for (int nt = 0; nt < 2; ++nt)
      #pragma unroll
      for (int r = 0; r < 4; ++r)
        o[q][nt][r] = fmaf(gate[r], aD[nt][r] - aC[nt][r], aC[nt][r]);
  }

  // ---- transpose via per-wave LDS scratch + wide NT stores.
  // Fragment layout: o[q][nt][r] is row kb*4+r, col (q*2+nt)*16+cidx.
  {
    float (*trw)[136] = tr[wv];
    #pragma unroll
    for (int r = 0; r < 4; ++r) {
      #pragma unroll
      for (int q = 0; q < 4; ++q)
        #pragma unroll
        for (int nt = 0; nt < 2; ++nt)
          trw[kb][(q * 2 + nt) * 16 + cidx] = o[q][nt][r];
      #pragma unroll
      for (int i = 0; i < 2; ++i) {
        const int ri = i * 2 + (lane >> 5);          // scratch row 0..3
        const f32x4 v = *reinterpret_cast<const f32x4*>(
            &trw[ri][(lane & 31) * 4]);
        float* dst = &out[((size_t)r0 + ri * 4 + r) * CF + (lane & 31) * 4];
        asm volatile("global_store_dwordx4 %0, %1, off nt"
                     :: "v"(dst), "v"(v) : "memory");
      }
    }
  }
}

}  // namespace

extern "C" void kernel_launch(void* const* d_in, const int* in_sizes, int n_in,
                              void* d_out, int out_size, void* d_ws, size_t ws_size,
                              hipStream_t stream) {
  const float* xd  = (const float*)d_in[0];
  const float* xc  = (const float*)d_in[1];
  const float* Wd  = (const float*)d_in[2];
  const float* Wc  = (const float*)d_in[3];
  const float* Wg1 = (const float*)d_in[4];
  const float* gma = (const float*)d_in[5];
  const float* bta = (const float*)d_in[6];
  const float* Wg2 = (const float*)d_in[7];
  float* out = (float*)d_out;
  short* ws  = (short*)d_ws;   // needs 60 KB

  const int N = in_sizes[0] / CD;

  convert_weights<<<dim3(15), dim3(256), 0, stream>>>(Wd, Wc, Wg1, ws);

  const int nblk = (N + 127) / 128;   // 128 rows per 8-wave block
  gate_fusion_mfma<<<dim3(nblk), dim3(512), 0, stream>>>(
      xd, xc, gma, bta, Wg2, ws, out, N);
}